// Round 10
// baseline (150.819 us; speedup 1.0000x reference)
//
#include <hip/hip_runtime.h>
#include <stdint.h>

typedef uint64_t u64;
typedef uint32_t u32;
typedef unsigned short u16;

#define NB    8
#define NQ    4096
#define NKEY  4096
#define CV    64
#define KSEL  16
#define GRD   64
#define NCELL (GRD * GRD)
#define HCELL 0.125f
#define GLO   -4.0f
#define CTGT  48
#define CMAX  128
#define PADU  (~(u64)0)

/* d_ws layout (459,008 B; R6 proved ws_size >= 524,544) */
#define WS_CS    256
#define WS_SKEY  (WS_CS + NB * NCELL * 4)     /* 131328 */
#define WS_SIDX  (WS_SKEY + NB * NKEY * 8)    /* 393472 */

__device__ __forceinline__ u64 shflxor_u64(u64 v, int m) {
    const u32 lo = __shfl_xor((int)(u32)v, m);
    const u32 hi = __shfl_xor((int)(u32)(v >> 32), m);
    return (((u64)hi) << 32) | lo;
}
__device__ __forceinline__ int mbcnt64(u64 m) {
    return (int)__builtin_amdgcn_mbcnt_hi((u32)(m >> 32),
               __builtin_amdgcn_mbcnt_lo((u32)m, 0));
}
__device__ __forceinline__ int cellof(float x) {
    int c = (int)floorf((x - GLO) * 8.0f);
    return c < 0 ? 0 : (c > GRD - 1 ? GRD - 1 : c);
}

/* full 64-lane bitonic sort, ascending (threshold order-statistic) */
__device__ __forceinline__ float lanesort64_f32(float v, int lane) {
#pragma unroll
    for (int k = 2; k <= 64; k <<= 1) {
#pragma unroll
        for (int j = k >> 1; j > 0; j >>= 1) {
            const float p = __shfl_xor(v, j);
            const bool up    = ((lane & k) == 0);
            const bool lower = ((lane & j) == 0);
            v = (lower == up) ? fminf(v, p) : fmaxf(v, p);
        }
    }
    return v;
}

/* EXACT smallest-16 SET of 64 lane values -> lanes 0..15 (unspecified order) */
__device__ __forceinline__ u64 top16of64(u64 v, int lane) {
#pragma unroll
    for (int k = 2; k <= 16; k <<= 1) {
#pragma unroll
        for (int j = k >> 1; j > 0; j >>= 1) {
            const u64 p = shflxor_u64(v, j);
            const bool up    = ((lane & k) == 0);
            const bool lower = ((lane & j) == 0);
            const u64 mn = v < p ? v : p, mx = v < p ? p : v;
            v = (lower == up) ? mn : mx;
        }
    }
    {   const u64 p = shflxor_u64(v, 16);
        const u64 mn = v < p ? v : p, mx = v < p ? p : v;
        v = ((lane & 16) == 0) ? mn : mx; }
#pragma unroll
    for (int j = 8; j > 0; j >>= 1) {
        const u64 p = shflxor_u64(v, j);
        const bool lower = ((lane & j) == 0);
        const bool dasc  = ((lane & 32) == 0);
        const u64 mn = v < p ? v : p, mx = v < p ? p : v;
        v = (lower == dasc) ? mn : mx;
    }
    {   const u64 p = shflxor_u64(v, 32);
        const u64 mn = v < p ? v : p, mx = v < p ? p : v;
        v = ((lane & 32) == 0) ? mn : mx; }
    return v;
}

/* ---------------- setup kernels ---------------- */
__global__ void k_zero(u32* __restrict__ cs) {
    cs[blockIdx.x * 256 + threadIdx.x] = 0u;
}
__global__ void k_count(const float* __restrict__ kg, u32* __restrict__ cs) {
    const int gid = blockIdx.x * 256 + threadIdx.x;     /* 32768 keys */
    const float2 kk = ((const float2*)kg)[gid];
    const int cell = cellof(kk.y) * GRD + cellof(kk.x);
    atomicAdd(&cs[(gid >> 12) * NCELL + cell], 1u);
}
__global__ void k_scan(u32* __restrict__ cs) {          /* 8 blocks x 64 thr */
    u32* c = cs + blockIdx.x * NCELL;
    const int lane = threadIdx.x & 63;
    u32 carry = 0;
#pragma unroll 1
    for (int i = 0; i < NCELL / 64; ++i) {
        const u32 v = c[i * 64 + lane];
        u32 s = v;
#pragma unroll
        for (int off = 1; off < 64; off <<= 1) {
            const u32 t = __shfl_up(s, off);
            if (lane >= off) s += t;
        }
        c[i * 64 + lane] = s - v + carry;               /* exclusive + carry */
        carry += (u32)__shfl(s, 63);
    }
}
__global__ void k_scatter(const float* __restrict__ kg, u32* __restrict__ cs,
                          float2* __restrict__ skey, u16* __restrict__ sidx) {
    const int gid = blockIdx.x * 256 + threadIdx.x;
    const float2 kk = ((const float2*)kg)[gid];
    const int b = gid >> 12;
    const int cell = cellof(kk.y) * GRD + cellof(kk.x);
    const u32 p = atomicAdd(&cs[b * NCELL + cell], 1u); /* cs -> end offsets */
    skey[b * NKEY + p] = kk;
    sidx[b * NKEY + p] = (u16)(gid & 4095);
}
__global__ void k_sums(const float* __restrict__ qw, const float* __restrict__ qb,
                       const float* __restrict__ kw, const float* __restrict__ kb,
                       float* __restrict__ w9) {
    const int h = threadIdx.x & 63;
    const float2 a = ((const float2*)qw)[h];
    const float2 c = ((const float2*)kw)[h];
    const float qbh = qb[h], kbh = kb[h];
    float s[9] = { a.x * c.x, a.y * c.x, qbh * c.x,
                   a.x * c.y, a.y * c.y, qbh * c.y,
                   a.x * kbh, a.y * kbh, qbh * kbh };
#pragma unroll
    for (int i = 0; i < 9; ++i)
#pragma unroll
        for (int off = 32; off; off >>= 1) s[i] += __shfl_xor(s[i], off);
    if (h == 0) {
#pragma unroll
        for (int i = 0; i < 9; ++i) w9[i] = s[i];
    }
}

/* ---------------- main: 1 wave per query ---------------- */
extern "C" __global__ __launch_bounds__(256, 8) void bev_grid(
    const float* __restrict__ qg, const float* __restrict__ kg,
    const float* __restrict__ vg, const float* __restrict__ w9,
    const u32* __restrict__ cs_g, const float2* __restrict__ skey_g,
    const u16* __restrict__ sidx_g, float* __restrict__ outg)
{
    __shared__ u64 cand[4][CMAX];                       /* 4 KB, per-wave */

    const int tid = threadIdx.x, wv = tid >> 6, lane = tid & 63;
    const int gw = blockIdx.x * 4 + wv;                 /* query id */
    const int b  = gw >> 12;
    const int qi = gw & 4095;

    const float2 qc = ((const float2*)qg)[(size_t)b * NQ + qi];
    const float qx = qc.x, qy = qc.y;
    const u32*    cs = cs_g   + b * NCELL;
    const float2* sk = skey_g + b * NKEY;
    const u16*    si = sidx_g + b * NKEY;
    u64* cd = cand[wv];

    const int qcx = __builtin_amdgcn_readfirstlane(cellof(qx));
    const int qcy = __builtin_amdgcn_readfirstlane(cellof(qy));

    /* ---- grow square until >= CTGT keys (scalar prefix reads) ---- */
    int R = 1, cx0, cx1, ry0, ry1, L;
#pragma unroll 1
    for (;;) {
        cx0 = qcx - R < 0 ? 0 : qcx - R;  cx1 = qcx + R > 63 ? 63 : qcx + R;
        ry0 = qcy - R < 0 ? 0 : qcy - R;  ry1 = qcy + R > 63 ? 63 : qcy + R;
        L = 0;
#pragma unroll 1
        for (int ry = ry0; ry <= ry1; ++ry) {
            const int c0 = ry * GRD + cx0;
            const int lo = c0 ? (int)cs[c0 - 1] : 0;
            L += (int)cs[ry * GRD + cx1] - lo;
        }
        if (L >= CTGT || R >= 63) break;
        ++R;
    }

    /* ---- pass 1: lane-min fold over square keys (cursor lane-spread) ---- */
    float mnv = __builtin_inff();
    int cum = 0;
#pragma unroll 1
    for (int ry = ry0; ry <= ry1; ++ry) {
        const int c0 = ry * GRD + cx0;
        const int lo = c0 ? (int)cs[c0 - 1] : 0;
        const int len = (int)cs[ry * GRD + cx1] - lo;
        int off = 0;
#pragma unroll 1
        while (off < len) {
            const int sl = cum & 63;
            const int n  = (64 - sl) < (len - off) ? (64 - sl) : (len - off);
            if (lane >= sl && lane < sl + n) {
                const float2 kk = sk[lo + off + lane - sl];
                const float dx = qx - kk.x, dy = qy - kk.y;
                mnv = fminf(mnv, fmaf(dx, dx, dy * dy));
            }
            off += n; cum += n;
        }
    }
    const float T = __shfl(lanesort64_f32(mnv, lane), 15);

    /* ---- pass 2: append all d2 <= T (>=16 guaranteed) ---- */
    int cnt = 0; cum = 0;
#pragma unroll 1
    for (int ry = ry0; ry <= ry1; ++ry) {
        const int c0 = ry * GRD + cx0;
        const int lo = c0 ? (int)cs[c0 - 1] : 0;
        const int len = (int)cs[ry * GRD + cx1] - lo;
        int off = 0;
#pragma unroll 1
        while (off < len) {
            const int sl = cum & 63;
            const int n  = (64 - sl) < (len - off) ? (64 - sl) : (len - off);
            const bool act = (lane >= sl) && (lane < sl + n);
            const int pos = lo + off + lane - sl;
            float d2 = __builtin_inff();
            if (act) {
                const float2 kk = sk[pos];
                const float dx = qx - kk.x, dy = qy - kk.y;
                d2 = fmaf(dx, dx, dy * dy);
            }
            const bool acc = act && (d2 <= T);
            const u64 mk = __ballot(acc);
            if (mk) {
                const int p = cnt + mbcnt64(mk);
                if (acc && p < CMAX)
                    cd[p] = (((u64)__float_as_uint(d2)) << 32) | (u32)si[pos];
                cnt += (int)__popcll(mk);
            }
            off += n; cum += n;
        }
    }
    if (cnt > CMAX) cnt = CMAX;

    /* ---- select: sort first 64, merge remainder in 48-chunks ---- */
    u64 myv = (lane < (cnt < 64 ? cnt : 64)) ? cd[lane] : PADU;
    myv = top16of64(myv, lane);
    {
        int base = 64, rem = cnt - 64;
#pragma unroll 1
        while (rem > 0) {
            const int take = rem < 48 ? rem : 48;
            const u64 inv = (lane < 16) ? myv
                          : ((lane - 16 < take) ? cd[base + lane - 16] : PADU);
            myv = top16of64(inv, lane);
            base += take; rem -= take;
        }
    }

    /* b16 = max of the 16 best (u64), d16 = its d2 */
    u64 b16; float d16f;
    {
        u64 m = myv;
#pragma unroll
        for (int off = 8; off; off >>= 1) { const u64 p = shflxor_u64(m, off); m = p > m ? p : m; }
        const u32 mlo = (u32)__builtin_amdgcn_readlane((int)(u32)m, 0);
        const u32 mhi = (u32)__builtin_amdgcn_readlane((int)(u32)(m >> 32), 0);
        b16 = (((u64)mhi) << 32) | mlo;
        d16f = __uint_as_float(mhi);
    }

    /* ---- exact ring extension ---- */
    int ecnt = 0;
    {
        auto refresh = [&]() {
            u64 m = myv;
#pragma unroll
            for (int off = 8; off; off >>= 1) { const u64 p = shflxor_u64(m, off); m = p > m ? p : m; }
            const u32 mlo = (u32)__builtin_amdgcn_readlane((int)(u32)m, 0);
            const u32 mhi = (u32)__builtin_amdgcn_readlane((int)(u32)(m >> 32), 0);
            b16 = (((u64)mhi) << 32) | mlo;
            d16f = __uint_as_float(mhi);
        };
        auto flush = [&]() {
#pragma unroll 1
            while (ecnt > 0) {
                const int take = ecnt < 48 ? ecnt : 48;
                const u64 inv = (lane < 16) ? myv
                              : ((lane - 16 < take) ? cd[ecnt - take + lane - 16] : PADU);
                myv = top16of64(inv, lane);
                ecnt -= take;
            }
            refresh();
        };
        auto doCell = [&](int cx, int cy) {
            /* exact box min-dist; edge cells half-infinite (clamped keys) */
            const float xlo = GLO + cx * HCELL, xhi = xlo + HCELL;
            const float ylo = GLO + cy * HCELL, yhi = ylo + HCELL;
            float dx = fmaxf((cx == 0) ? 0.f : (xlo - qx), (cx == GRD - 1) ? 0.f : (qx - xhi));
            float dy = fmaxf((cy == 0) ? 0.f : (ylo - qy), (cy == GRD - 1) ? 0.f : (qy - yhi));
            dx = fmaxf(dx, 0.f); dy = fmaxf(dy, 0.f);
            if (fmaf(dx, dx, dy * dy) > d16f) return;
            const int c = cy * GRD + cx;
            const int lo = c ? (int)cs[c - 1] : 0;
            const int len = (int)cs[c] - lo;
#pragma unroll 1
            for (int off = 0; off < len; off += 64) {
                const bool act = lane < (len - off < 64 ? len - off : 64);
                const int pos = lo + off + lane;
                u64 pk = PADU;
                if (act) {
                    const float2 kk = sk[pos];
                    const float ddx = qx - kk.x, ddy = qy - kk.y;
                    const float d2 = fmaf(ddx, ddx, ddy * ddy);
                    pk = (((u64)__float_as_uint(d2)) << 32) | (u32)si[pos];
                }
                const bool acc = act && (pk < b16);
                const u64 mk = __ballot(acc);
                if (mk) {
                    const int p = ecnt + mbcnt64(mk);
                    if (acc && p < CMAX) cd[p] = pk;
                    ecnt += (int)__popcll(mk);
                    if (ecnt > CMAX) ecnt = CMAX;
                }
            }
            if (ecnt >= 48) flush();
        };

        int D = R + 1;
#pragma unroll 1
        for (;;) {
            const float rb = (float)(D - 1) * HCELL;
            if (rb * rb > d16f) break;
            const int xa = qcx - D, xb = qcx + D, ya = qcy - D, yb = qcy + D;
            if (xa < 0 && xb > 63 && ya < 0 && yb > 63) break;
            const int cxa = xa < 0 ? 0 : xa, cxb = xb > 63 ? 63 : xb;
            if (ya >= 0) for (int cx = cxa; cx <= cxb; ++cx) doCell(cx, ya);
            if (yb <= 63) for (int cx = cxa; cx <= cxb; ++cx) doCell(cx, yb);
            const int cya = (ya + 1) < 0 ? 0 : ya + 1, cyb = (yb - 1) > 63 ? 63 : yb - 1;
            if (xa >= 0) for (int cy = cya; cy <= cyb; ++cy) doCell(xa, cy);
            if (xb <= 63) for (int cy = cya; cy <= cyb; ++cy) doCell(xb, cy);
            ++D;
        }
        if (ecnt > 0) flush();
    }

    /* ---- epilogue: affine scores, width-16 softmax, V gather ---- */
    const u32 myidx = (u32)myv;
    const float A  = fmaf(qx, w9[0], fmaf(qy, w9[1], w9[2]));
    const float Bb = fmaf(qx, w9[3], fmaf(qy, w9[4], w9[5]));
    const float Cc = fmaf(qx, w9[6], fmaf(qy, w9[7], w9[8]));

    const float2* kp = (const float2*)kg + (size_t)b * NKEY;
    const int sel = (lane < KSEL) ? (int)myidx : 0;
    const float2 kc = kp[sel];
    const float score = fmaf(A, kc.x, fmaf(Bb, kc.y, Cc));
    float mx = score;
#pragma unroll
    for (int off = 8; off; off >>= 1) mx = fmaxf(mx, __shfl_xor(mx, off));
    const float e = __expf(score - mx);
    float sum = e;
#pragma unroll
    for (int off = 8; off; off >>= 1) sum += __shfl_xor(sum, off);
    const float w = e / sum;                            /* valid lanes 0..15 */

    const float* vb = vg + (size_t)b * NKEY * CV;
    float acc = 0.f;
#pragma unroll
    for (int s = 0; s < KSEL; ++s) {
        const u32 id   = (u32)__builtin_amdgcn_readlane((int)myidx, s);
        const float ws = __uint_as_float(
            (u32)__builtin_amdgcn_readlane((int)__float_as_uint(w), s));
        acc = fmaf(ws, vb[(size_t)id * CV + lane], acc);
    }
    outg[((size_t)b * NQ + qi) * CV + lane] = acc;
}

extern "C" void kernel_launch(void* const* d_in, const int* in_sizes, int n_in,
                              void* d_out, int out_size, void* d_ws, size_t ws_size,
                              hipStream_t stream) {
    const float* q  = (const float*)d_in[0];
    const float* k  = (const float*)d_in[1];
    const float* v  = (const float*)d_in[2];
    const float* qw = (const float*)d_in[3];
    const float* qb = (const float*)d_in[4];
    const float* kw = (const float*)d_in[5];
    const float* kb = (const float*)d_in[6];
    /* d_in[7] = top_k (always 16; compile-time) */
    float* out = (float*)d_out;

    float*  w9   = (float*)d_ws;
    u32*    cs   = (u32*)((char*)d_ws + WS_CS);
    float2* skey = (float2*)((char*)d_ws + WS_SKEY);
    u16*    sidx = (u16*)((char*)d_ws + WS_SIDX);

    hipLaunchKernelGGL(k_zero,    dim3(NB * NCELL / 256), dim3(256), 0, stream, cs);
    hipLaunchKernelGGL(k_count,   dim3(NB * NKEY / 256),  dim3(256), 0, stream, k, cs);
    hipLaunchKernelGGL(k_scan,    dim3(NB), dim3(64), 0, stream, cs);
    hipLaunchKernelGGL(k_scatter, dim3(NB * NKEY / 256),  dim3(256), 0, stream, k, cs, skey, sidx);
    hipLaunchKernelGGL(k_sums,    dim3(1), dim3(64), 0, stream, qw, qb, kw, kb, w9);
    hipLaunchKernelGGL(bev_grid,  dim3(NB * NQ / 4), dim3(256), 0, stream,
                       q, k, v, w9, cs, skey, sidx, out);
}